// Round 1
// baseline (521.018 us; speedup 1.0000x reference)
//
#include <hip/hip_runtime.h>
#include <cstdint>
#include <cstddef>

#define NN 100000
#define NE 1600000
#define DD 128
#define EPSV 1e-5f

// ---------------------------------------------------------------------------
// Edge dtype detection: reference says int64, but JAX default x64-off often
// yields int32. For int64 (little-endian, values < 2^31) every odd 32-bit
// word is 0. Sample 4096 odd words; any nonzero => int32 layout.
// ---------------------------------------------------------------------------
__global__ void detect_kernel(const unsigned* __restrict__ raw, int* __restrict__ flag) {
    int i = blockIdx.x * blockDim.x + threadIdx.x;
    if (i >= 4096) return;
    size_t idx = (size_t)i * 780 + 1;           // odd, max 3,194,101 < 2*NE
    if (raw[idx] != 0) atomicOr(flag, 1);
}

__global__ void convert_kernel(const int* __restrict__ raw, int* __restrict__ e32,
                               const int* __restrict__ flag) {
    const int is32 = *flag;
    const int stride = gridDim.x * blockDim.x;
    for (int i = blockIdx.x * blockDim.x + threadIdx.x; i < 2 * NE; i += stride)
        e32[i] = is32 ? raw[i] : raw[2 * (size_t)i];   // int64: take low word
}

// count in-degree (excluding self-loop)
__global__ void count_kernel(const int* __restrict__ e32, int* __restrict__ cnt) {
    const int stride = gridDim.x * blockDim.x;
    for (int e = blockIdx.x * blockDim.x + threadIdx.x; e < NE; e += stride)
        atomicAdd(&cnt[e32[NE + e]], 1);
}

// bucket allocation: block-scan of counts + one atomic per block for base.
// Also writes fill cursors and dis = rsqrt(deg) with deg = cnt + 1 (self-loop).
__global__ void alloc_kernel(const int* __restrict__ cnt, int* __restrict__ start,
                             int* __restrict__ fill, float* __restrict__ dis,
                             int* __restrict__ cursor) {
    __shared__ int sdata[256];
    __shared__ int sbase;
    const int tid = threadIdx.x;
    const int v = blockIdx.x * 256 + tid;
    const int c = (v < NN) ? cnt[v] : 0;
    sdata[tid] = c;
    __syncthreads();
    #pragma unroll
    for (int off = 1; off < 256; off <<= 1) {
        int t = (tid >= off) ? sdata[tid - off] : 0;
        __syncthreads();
        sdata[tid] += t;
        __syncthreads();
    }
    const int excl = sdata[tid] - c;
    const int total = sdata[255];
    if (tid == 0) sbase = atomicAdd(cursor, total);
    __syncthreads();
    if (v < NN) {
        const int st = sbase + excl;
        start[v] = st;
        fill[v] = st;
        dis[v] = rsqrtf((float)(c + 1));
    }
}

// scatter edge sources into per-dst buckets
__global__ void scatter_kernel(const int* __restrict__ e32, int* __restrict__ fill,
                               int* __restrict__ ssrc) {
    const int stride = gridDim.x * blockDim.x;
    for (int e = blockIdx.x * blockDim.x + threadIdx.x; e < NE; e += stride) {
        const int s = e32[e];
        const int d = e32[NE + e];
        const int p = atomicAdd(&fill[d], 1);
        ssrc[p] = s;
    }
}

// xw = x @ W.  W (64KB) + 32 x-rows (16KB) staged in LDS. Each wave computes
// 8 rows; lane l holds output cols (2l, 2l+1). 512 blocks -> 2 blocks/CU.
__global__ __launch_bounds__(256) void gemm_kernel(const float* __restrict__ x,
                                                   const float* __restrict__ W,
                                                   float* __restrict__ xw) {
    __shared__ float Wl[DD * DD];   // 64 KB
    __shared__ float Xl[32 * DD];   // 16 KB
    const int tid = threadIdx.x;
    for (int i = tid * 4; i < DD * DD; i += 1024)
        *(float4*)(Wl + i) = *(const float4*)(W + i);
    const int wave = tid >> 6, lane = tid & 63;
    for (int grp = blockIdx.x; grp < NN / 32; grp += gridDim.x) {
        const size_t base = (size_t)grp * 32;
        __syncthreads();   // W ready (first iter) / previous Xl readers done
        for (int i = tid * 4; i < 32 * DD; i += 1024)
            *(float4*)(Xl + i) = *(const float4*)(x + base * DD + i);
        __syncthreads();
        float ax[8], ay[8];
        #pragma unroll
        for (int r = 0; r < 8; ++r) { ax[r] = 0.f; ay[r] = 0.f; }
        const float* Xrow = Xl + wave * 8 * DD;
        for (int k = 0; k < DD; k += 4) {
            const float2 w0 = *(const float2*)(Wl + (k + 0) * DD + 2 * lane);
            const float2 w1 = *(const float2*)(Wl + (k + 1) * DD + 2 * lane);
            const float2 w2 = *(const float2*)(Wl + (k + 2) * DD + 2 * lane);
            const float2 w3 = *(const float2*)(Wl + (k + 3) * DD + 2 * lane);
            #pragma unroll
            for (int r = 0; r < 8; ++r) {
                const float4 xv = *(const float4*)(Xrow + r * DD + k);
                ax[r] = fmaf(xv.x, w0.x, ax[r]); ay[r] = fmaf(xv.x, w0.y, ay[r]);
                ax[r] = fmaf(xv.y, w1.x, ax[r]); ay[r] = fmaf(xv.y, w1.y, ay[r]);
                ax[r] = fmaf(xv.z, w2.x, ax[r]); ay[r] = fmaf(xv.z, w2.y, ay[r]);
                ax[r] = fmaf(xv.w, w3.x, ax[r]); ay[r] = fmaf(xv.w, w3.y, ay[r]);
            }
        }
        #pragma unroll
        for (int r = 0; r < 8; ++r) {
            float2 o; o.x = ax[r]; o.y = ay[r];
            *(float2*)(xw + (base + wave * 8 + r) * DD + 2 * lane) = o;
        }
    }
}

// One wave per node: gather-accumulate in-edges, + self-loop + bias +
// residual, then fused LayerNorm + ReLU. Lane l owns cols (2l, 2l+1).
__global__ void agg_ln_kernel(const float* __restrict__ xw, const float* __restrict__ x,
                              const int* __restrict__ ssrc, const int* __restrict__ start,
                              const int* __restrict__ cnt, const float* __restrict__ dis,
                              const float* __restrict__ b, const float* __restrict__ g,
                              const float* __restrict__ be, float* __restrict__ out) {
    const int wave = threadIdx.x >> 6, lane = threadIdx.x & 63;
    const int node = blockIdx.x * 4 + wave;
    if (node >= NN) return;
    const float dv = dis[node];
    const float2 xself = *(const float2*)(xw + (size_t)node * DD + 2 * lane);
    float accx = dv * dv * xself.x;
    float accy = dv * dv * xself.y;
    const int s0 = start[node];
    const int c = cnt[node];
    for (int chunk = 0; chunk < c; chunk += 64) {
        const int rem = c - chunk;
        int sj = 0; float dsj = 0.f;
        if (lane < rem) {
            sj = ssrc[s0 + chunk + lane];
            dsj = dis[sj];
        }
        const int m = rem < 64 ? rem : 64;
        for (int j = 0; j < m; ++j) {
            const int s = __builtin_amdgcn_readlane(sj, j);
            const float w = __uint_as_float(__builtin_amdgcn_readlane(__float_as_uint(dsj), j)) * dv;
            const float2 v = *(const float2*)(xw + (size_t)s * DD + 2 * lane);
            accx = fmaf(w, v.x, accx);
            accy = fmaf(w, v.y, accy);
        }
    }
    const float2 xr = *(const float2*)(x + (size_t)node * DD + 2 * lane);
    const float2 bb = *(const float2*)(b + 2 * lane);
    const float h0 = accx + bb.x + xr.x;
    const float h1 = accy + bb.y + xr.y;
    float sum = h0 + h1;
    #pragma unroll
    for (int off = 32; off; off >>= 1) sum += __shfl_xor(sum, off);
    const float mu = sum * (1.f / 128.f);
    const float e0 = h0 - mu, e1 = h1 - mu;
    float s2 = e0 * e0 + e1 * e1;
    #pragma unroll
    for (int off = 32; off; off >>= 1) s2 += __shfl_xor(s2, off);
    const float inv = rsqrtf(s2 * (1.f / 128.f) + EPSV);
    const float2 gg = *(const float2*)(g + 2 * lane);
    const float2 bt = *(const float2*)(be + 2 * lane);
    float2 o;
    o.x = fmaxf(0.f, e0 * inv * gg.x + bt.x);
    o.y = fmaxf(0.f, e1 * inv * gg.y + bt.y);
    *(float2*)(out + (size_t)node * DD + 2 * lane) = o;
}

extern "C" void kernel_launch(void* const* d_in, const int* in_sizes, int n_in,
                              void* d_out, int out_size, void* d_ws, size_t ws_size,
                              hipStream_t stream) {
    const float* x  = (const float*)d_in[0];
    const int*   ei = (const int*)d_in[1];      // raw; width detected on device
    const float* W  = (const float*)d_in[2];
    const float* b  = (const float*)d_in[3];
    const float* g  = (const float*)d_in[4];
    const float* be = (const float*)d_in[5];
    float* out = (float*)d_out;

    char* ws = (char*)d_ws;
    size_t off = 0;
    float* xw    = (float*)(ws + off); off += (size_t)NN * DD * 4;   // 51.2 MB
    int*   e32   = (int*)(ws + off);   off += (size_t)2 * NE * 4;    // 12.8 MB
    int*   ssrc  = (int*)(ws + off);   off += (size_t)NE * 4;        // 6.4 MB
    int*   cnt   = (int*)(ws + off);   off += (size_t)NN * 4;
    int*   start = (int*)(ws + off);   off += (size_t)NN * 4;
    int*   fill  = (int*)(ws + off);   off += (size_t)NN * 4;
    float* dis   = (float*)(ws + off); off += (size_t)NN * 4;
    int*   flagc = (int*)(ws + off);   off += 256;                   // [flag, cursor]

    hipMemsetAsync(cnt, 0, (size_t)NN * 4, stream);
    hipMemsetAsync(flagc, 0, 256, stream);

    detect_kernel<<<16, 256, 0, stream>>>((const unsigned*)ei, flagc);
    convert_kernel<<<2048, 256, 0, stream>>>(ei, e32, flagc);
    count_kernel<<<2048, 256, 0, stream>>>(e32, cnt);
    alloc_kernel<<<(NN + 255) / 256, 256, 0, stream>>>(cnt, start, fill, dis, flagc + 1);
    scatter_kernel<<<2048, 256, 0, stream>>>(e32, fill, ssrc);
    gemm_kernel<<<512, 256, 0, stream>>>(x, W, xw);
    agg_ln_kernel<<<NN / 4, 256, 0, stream>>>(xw, x, ssrc, start, cnt, dis, b, g, be, out);
}

// Round 2
// 458.074 us; speedup vs baseline: 1.1374x; 1.1374x over previous
//
#include <hip/hip_runtime.h>
#include <cstdint>
#include <cstddef>

#define NN 100000
#define NE 1600000
#define DD 128
#define EPSV 1e-5f
#define NPART 8
#define PSIZE (NN / NPART)          // 12500 nodes per partition
#define NCHUNK 256
#define CSZ (NE / NCHUNK)           // 6250 edges per chunk

// ---------------------------------------------------------------------------
// Edge dtype detection: reference says int64, but JAX default x64-off often
// yields int32. For int64 (little-endian, values < 2^31) every odd 32-bit
// word is 0. Sample 4096 odd words; any nonzero => int32 layout.
// ---------------------------------------------------------------------------
__global__ void detect_kernel(const unsigned* __restrict__ raw, int* __restrict__ flag) {
    int i = blockIdx.x * blockDim.x + threadIdx.x;
    if (i >= 4096) return;
    size_t idx = (size_t)i * 780 + 1;           // odd, max 3,194,101 < 2*NE
    if (raw[idx] != 0) atomicOr(flag, 1);
}

__global__ void convert_kernel(const int* __restrict__ raw, int* __restrict__ e32,
                               const int* __restrict__ flag) {
    const int is32 = *flag;
    const int stride = gridDim.x * blockDim.x;
    for (int i = blockIdx.x * blockDim.x + threadIdx.x; i < 2 * NE; i += stride)
        e32[i] = is32 ? raw[i] : raw[2 * (size_t)i];   // int64: take low word
}

// count in-degree (excluding self-loop), dst-partitioned so each partition's
// cnt slice is only touched by blocks b with b%8==p (one XCD, L2-local).
__global__ void count_kernel(const int* __restrict__ e32, int* __restrict__ cnt) {
    const int part = blockIdx.x & (NPART - 1);
    const int chunk = blockIdx.x >> 3;
    const int lo = part * PSIZE, hi = lo + PSIZE;
    const int e0 = chunk * CSZ, e1 = e0 + CSZ;
    for (int e = e0 + threadIdx.x; e < e1; e += 256) {
        const int d = e32[NE + e];
        if (d >= lo && d < hi) atomicAdd(&cnt[d], 1);
    }
}

// bucket allocation: block-scan of counts + one atomic per block for base.
// Also writes fill cursors and dis = rsqrt(deg) with deg = cnt + 1 (self-loop).
__global__ void alloc_kernel(const int* __restrict__ cnt, int* __restrict__ start,
                             int* __restrict__ fill, float* __restrict__ dis,
                             int* __restrict__ cursor) {
    __shared__ int sdata[256];
    __shared__ int sbase;
    const int tid = threadIdx.x;
    const int v = blockIdx.x * 256 + tid;
    const int c = (v < NN) ? cnt[v] : 0;
    sdata[tid] = c;
    __syncthreads();
    #pragma unroll
    for (int off = 1; off < 256; off <<= 1) {
        int t = (tid >= off) ? sdata[tid - off] : 0;
        __syncthreads();
        sdata[tid] += t;
        __syncthreads();
    }
    const int excl = sdata[tid] - c;
    const int total = sdata[255];
    if (tid == 0) sbase = atomicAdd(cursor, total);
    __syncthreads();
    if (v < NN) {
        const int st = sbase + excl;
        start[v] = st;
        fill[v] = st;
        dis[v] = rsqrtf((float)(c + 1));
    }
}

// scatter edge sources into per-dst buckets, dst-partitioned like count.
// NOTE: buckets are NOT globally node-ordered (alloc bases come from an
// atomic cursor), but each partition's writes land in regions allocated by
// blocks; the key property is all writers of partition p are on one XCD.
__global__ void scatter_kernel(const int* __restrict__ e32, int* __restrict__ fill,
                               int* __restrict__ ssrc) {
    const int part = blockIdx.x & (NPART - 1);
    const int chunk = blockIdx.x >> 3;
    const int lo = part * PSIZE, hi = lo + PSIZE;
    const int e0 = chunk * CSZ, e1 = e0 + CSZ;
    for (int e = e0 + threadIdx.x; e < e1; e += 256) {
        const int d = e32[NE + e];
        if (d >= lo && d < hi) {
            const int s = e32[e];
            const int p = atomicAdd(&fill[d], 1);
            ssrc[p] = s;
        }
    }
}

// xw = x @ W.  W (64KB) + 32 x-rows (16KB) staged in LDS. Each wave computes
// 8 rows; lane l holds output cols (2l, 2l+1). 512 blocks -> 2 blocks/CU.
__global__ __launch_bounds__(256) void gemm_kernel(const float* __restrict__ x,
                                                   const float* __restrict__ W,
                                                   float* __restrict__ xw) {
    __shared__ float Wl[DD * DD];   // 64 KB
    __shared__ float Xl[32 * DD];   // 16 KB
    const int tid = threadIdx.x;
    for (int i = tid * 4; i < DD * DD; i += 1024)
        *(float4*)(Wl + i) = *(const float4*)(W + i);
    const int wave = tid >> 6, lane = tid & 63;
    for (int grp = blockIdx.x; grp < NN / 32; grp += gridDim.x) {
        const size_t base = (size_t)grp * 32;
        __syncthreads();   // W ready (first iter) / previous Xl readers done
        for (int i = tid * 4; i < 32 * DD; i += 1024)
            *(float4*)(Xl + i) = *(const float4*)(x + base * DD + i);
        __syncthreads();
        float ax[8], ay[8];
        #pragma unroll
        for (int r = 0; r < 8; ++r) { ax[r] = 0.f; ay[r] = 0.f; }
        const float* Xrow = Xl + wave * 8 * DD;
        for (int k = 0; k < DD; k += 4) {
            const float2 w0 = *(const float2*)(Wl + (k + 0) * DD + 2 * lane);
            const float2 w1 = *(const float2*)(Wl + (k + 1) * DD + 2 * lane);
            const float2 w2 = *(const float2*)(Wl + (k + 2) * DD + 2 * lane);
            const float2 w3 = *(const float2*)(Wl + (k + 3) * DD + 2 * lane);
            #pragma unroll
            for (int r = 0; r < 8; ++r) {
                const float4 xv = *(const float4*)(Xrow + r * DD + k);
                ax[r] = fmaf(xv.x, w0.x, ax[r]); ay[r] = fmaf(xv.x, w0.y, ay[r]);
                ax[r] = fmaf(xv.y, w1.x, ax[r]); ay[r] = fmaf(xv.y, w1.y, ay[r]);
                ax[r] = fmaf(xv.z, w2.x, ax[r]); ay[r] = fmaf(xv.z, w2.y, ay[r]);
                ax[r] = fmaf(xv.w, w3.x, ax[r]); ay[r] = fmaf(xv.w, w3.y, ay[r]);
            }
        }
        #pragma unroll
        for (int r = 0; r < 8; ++r) {
            float2 o; o.x = ax[r]; o.y = ay[r];
            *(float2*)(xw + (base + wave * 8 + r) * DD + 2 * lane) = o;
        }
    }
}

// One wave per node: gather-accumulate in-edges, + self-loop + bias +
// residual, then fused LayerNorm + ReLU. Lane l owns cols (2l, 2l+1).
__global__ void agg_ln_kernel(const float* __restrict__ xw, const float* __restrict__ x,
                              const int* __restrict__ ssrc, const int* __restrict__ start,
                              const int* __restrict__ cnt, const float* __restrict__ dis,
                              const float* __restrict__ b, const float* __restrict__ g,
                              const float* __restrict__ be, float* __restrict__ out) {
    const int wave = threadIdx.x >> 6, lane = threadIdx.x & 63;
    const int node = blockIdx.x * 4 + wave;
    if (node >= NN) return;
    const float dv = dis[node];
    const float2 xself = *(const float2*)(xw + (size_t)node * DD + 2 * lane);
    float accx = dv * dv * xself.x;
    float accy = dv * dv * xself.y;
    const int s0 = start[node];
    const int c = cnt[node];
    for (int chunk = 0; chunk < c; chunk += 64) {
        const int rem = c - chunk;
        int sj = 0; float dsj = 0.f;
        if (lane < rem) {
            sj = ssrc[s0 + chunk + lane];
            dsj = dis[sj];
        }
        const int m = rem < 64 ? rem : 64;
        for (int j = 0; j < m; ++j) {
            const int s = __builtin_amdgcn_readlane(sj, j);
            const float w = __uint_as_float(__builtin_amdgcn_readlane(__float_as_uint(dsj), j)) * dv;
            const float2 v = *(const float2*)(xw + (size_t)s * DD + 2 * lane);
            accx = fmaf(w, v.x, accx);
            accy = fmaf(w, v.y, accy);
        }
    }
    const float2 xr = *(const float2*)(x + (size_t)node * DD + 2 * lane);
    const float2 bb = *(const float2*)(b + 2 * lane);
    const float h0 = accx + bb.x + xr.x;
    const float h1 = accy + bb.y + xr.y;
    float sum = h0 + h1;
    #pragma unroll
    for (int off = 32; off; off >>= 1) sum += __shfl_xor(sum, off);
    const float mu = sum * (1.f / 128.f);
    const float e0 = h0 - mu, e1 = h1 - mu;
    float s2 = e0 * e0 + e1 * e1;
    #pragma unroll
    for (int off = 32; off; off >>= 1) s2 += __shfl_xor(s2, off);
    const float inv = rsqrtf(s2 * (1.f / 128.f) + EPSV);
    const float2 gg = *(const float2*)(g + 2 * lane);
    const float2 bt = *(const float2*)(be + 2 * lane);
    float2 o;
    o.x = fmaxf(0.f, e0 * inv * gg.x + bt.x);
    o.y = fmaxf(0.f, e1 * inv * gg.y + bt.y);
    *(float2*)(out + (size_t)node * DD + 2 * lane) = o;
}

extern "C" void kernel_launch(void* const* d_in, const int* in_sizes, int n_in,
                              void* d_out, int out_size, void* d_ws, size_t ws_size,
                              hipStream_t stream) {
    const float* x  = (const float*)d_in[0];
    const int*   ei = (const int*)d_in[1];      // raw; width detected on device
    const float* W  = (const float*)d_in[2];
    const float* b  = (const float*)d_in[3];
    const float* g  = (const float*)d_in[4];
    const float* be = (const float*)d_in[5];
    float* out = (float*)d_out;

    char* ws = (char*)d_ws;
    size_t off = 0;
    float* xw    = (float*)(ws + off); off += (size_t)NN * DD * 4;   // 51.2 MB
    int*   e32   = (int*)(ws + off);   off += (size_t)2 * NE * 4;    // 12.8 MB
    int*   ssrc  = (int*)(ws + off);   off += (size_t)NE * 4;        // 6.4 MB
    int*   cnt   = (int*)(ws + off);   off += (size_t)NN * 4;
    int*   start = (int*)(ws + off);   off += (size_t)NN * 4;
    int*   fill  = (int*)(ws + off);   off += (size_t)NN * 4;
    float* dis   = (float*)(ws + off); off += (size_t)NN * 4;
    int*   flagc = (int*)(ws + off);   off += 256;                   // [flag, cursor]

    hipMemsetAsync(cnt, 0, (size_t)NN * 4, stream);
    hipMemsetAsync(flagc, 0, 256, stream);

    detect_kernel<<<16, 256, 0, stream>>>((const unsigned*)ei, flagc);
    convert_kernel<<<2048, 256, 0, stream>>>(ei, e32, flagc);
    count_kernel<<<NPART * NCHUNK, 256, 0, stream>>>(e32, cnt);
    alloc_kernel<<<(NN + 255) / 256, 256, 0, stream>>>(cnt, start, fill, dis, flagc + 1);
    scatter_kernel<<<NPART * NCHUNK, 256, 0, stream>>>(e32, fill, ssrc);
    gemm_kernel<<<512, 256, 0, stream>>>(x, W, xw);
    agg_ln_kernel<<<NN / 4, 256, 0, stream>>>(xw, x, ssrc, start, cnt, dis, b, g, be, out);
}

// Round 3
// 451.536 us; speedup vs baseline: 1.1539x; 1.0145x over previous
//
#include <hip/hip_runtime.h>
#include <cstdint>
#include <cstddef>

#define NN 100000
#define NE 1600000
#define DD 128
#define EPSV 1e-5f
#define NPART 8
#define PSIZE (NN / NPART)          // 12500 nodes per partition
#define NCHUNK 256
#define CSZ (NE / NCHUNK)           // 6250 edges per chunk

// RNE float->bf16 (no NaN handling; inputs are finite randn-scale values)
static __device__ inline unsigned short f2bf(float f) {
    unsigned u = __float_as_uint(f);
    unsigned r = (u + 0x7fffu + ((u >> 16) & 1u)) >> 16;
    return (unsigned short)r;
}

// ---------------------------------------------------------------------------
// Edge dtype detection: reference says int64, but JAX default x64-off often
// yields int32. For int64 (little-endian, values < 2^31) every odd 32-bit
// word is 0. Sample 4096 odd words; any nonzero => int32 layout.
// ---------------------------------------------------------------------------
__global__ void detect_kernel(const unsigned* __restrict__ raw, int* __restrict__ flag) {
    int i = blockIdx.x * blockDim.x + threadIdx.x;
    if (i >= 4096) return;
    size_t idx = (size_t)i * 780 + 1;           // odd, max 3,194,101 < 2*NE
    if (raw[idx] != 0) atomicOr(flag, 1);
}

// Fused: edge-index normalization to int32 AND x -> bf16 copy (for the gather)
__global__ void convert_kernel(const int* __restrict__ raw, int* __restrict__ e32,
                               const int* __restrict__ flag,
                               const float* __restrict__ x, unsigned short* __restrict__ xb) {
    const int is32 = *flag;
    const int stride = gridDim.x * blockDim.x;
    const int tid0 = blockIdx.x * blockDim.x + threadIdx.x;
    for (int i = tid0; i < 2 * NE; i += stride)
        e32[i] = is32 ? raw[i] : raw[2 * (size_t)i];   // int64: take low word
    for (int i = tid0; i < NN * DD / 4; i += stride) {
        const float4 v = *(const float4*)(x + (size_t)i * 4);
        ushort4 o;
        o.x = f2bf(v.x); o.y = f2bf(v.y); o.z = f2bf(v.z); o.w = f2bf(v.w);
        *(ushort4*)(xb + (size_t)i * 4) = o;
    }
}

// count in-degree (excluding self-loop), dst-partitioned so each partition's
// cnt slice is only touched by blocks b with b%8==p (one XCD, L2-local).
__global__ void count_kernel(const int* __restrict__ e32, int* __restrict__ cnt) {
    const int part = blockIdx.x & (NPART - 1);
    const int chunk = blockIdx.x >> 3;
    const int lo = part * PSIZE, hi = lo + PSIZE;
    const int e0 = chunk * CSZ, e1 = e0 + CSZ;
    for (int e = e0 + threadIdx.x; e < e1; e += 256) {
        const int d = e32[NE + e];
        if (d >= lo && d < hi) atomicAdd(&cnt[d], 1);
    }
}

// bucket allocation: block-scan of counts + one atomic per block for base.
// Also writes fill cursors and dis = rsqrt(deg) with deg = cnt + 1 (self-loop).
__global__ void alloc_kernel(const int* __restrict__ cnt, int* __restrict__ start,
                             int* __restrict__ fill, float* __restrict__ dis,
                             int* __restrict__ cursor) {
    __shared__ int sdata[256];
    __shared__ int sbase;
    const int tid = threadIdx.x;
    const int v = blockIdx.x * 256 + tid;
    const int c = (v < NN) ? cnt[v] : 0;
    sdata[tid] = c;
    __syncthreads();
    #pragma unroll
    for (int off = 1; off < 256; off <<= 1) {
        int t = (tid >= off) ? sdata[tid - off] : 0;
        __syncthreads();
        sdata[tid] += t;
        __syncthreads();
    }
    const int excl = sdata[tid] - c;
    const int total = sdata[255];
    if (tid == 0) sbase = atomicAdd(cursor, total);
    __syncthreads();
    if (v < NN) {
        const int st = sbase + excl;
        start[v] = st;
        fill[v] = st;
        dis[v] = rsqrtf((float)(c + 1));
    }
}

// scatter edge sources into per-dst buckets, dst-partitioned like count.
__global__ void scatter_kernel(const int* __restrict__ e32, int* __restrict__ fill,
                               int* __restrict__ ssrc) {
    const int part = blockIdx.x & (NPART - 1);
    const int chunk = blockIdx.x >> 3;
    const int lo = part * PSIZE, hi = lo + PSIZE;
    const int e0 = chunk * CSZ, e1 = e0 + CSZ;
    for (int e = e0 + threadIdx.x; e < e1; e += 256) {
        const int d = e32[NE + e];
        if (d >= lo && d < hi) {
            const int s = e32[e];
            const int p = atomicAdd(&fill[d], 1);
            ssrc[p] = s;
        }
    }
}

// One wave per node: gather bf16 x rows, f32-accumulate
//   agg[n] = sum_e dis[s]*dis[n]*x[s] + dis[n]^2*x[n]
// store bf16. Lane l owns cols (2l, 2l+1).
__global__ void agg_kernel(const unsigned short* __restrict__ xb,
                           const int* __restrict__ ssrc, const int* __restrict__ start,
                           const int* __restrict__ cnt, const float* __restrict__ dis,
                           unsigned short* __restrict__ agg) {
    const int wave = threadIdx.x >> 6, lane = threadIdx.x & 63;
    const int node = blockIdx.x * 4 + wave;
    if (node >= NN) return;
    const float dv = dis[node];
    const unsigned us = *(const unsigned*)(xb + (size_t)node * DD + 2 * lane);
    float accx = dv * dv * __uint_as_float(us << 16);
    float accy = dv * dv * __uint_as_float(us & 0xffff0000u);
    const int s0 = start[node];
    const int c = cnt[node];
    for (int chunk = 0; chunk < c; chunk += 64) {
        const int rem = c - chunk;
        int sj = 0; float dsj = 0.f;
        if (lane < rem) {
            sj = ssrc[s0 + chunk + lane];
            dsj = dis[sj];
        }
        const int m = rem < 64 ? rem : 64;
        for (int j = 0; j < m; ++j) {
            const int s = __builtin_amdgcn_readlane(sj, j);
            const float w = __uint_as_float(__builtin_amdgcn_readlane(__float_as_uint(dsj), j)) * dv;
            const unsigned uv = *(const unsigned*)(xb + (size_t)s * DD + 2 * lane);
            accx = fmaf(w, __uint_as_float(uv << 16), accx);
            accy = fmaf(w, __uint_as_float(uv & 0xffff0000u), accy);
        }
    }
    ushort2 st; st.x = f2bf(accx); st.y = f2bf(accy);
    *(ushort2*)(agg + (size_t)node * DD + 2 * lane) = st;
}

// h = agg @ W + b + x; LayerNorm; ReLU. W (64KB f32) + 32 agg rows
// (expanded to f32, 16KB) in LDS. Each wave computes 8 rows; lane l holds
// output cols (2l, 2l+1). 512 blocks -> 2 blocks/CU.
__global__ __launch_bounds__(256) void gemm2_kernel(const unsigned short* __restrict__ agg,
                                                    const float* __restrict__ x,
                                                    const float* __restrict__ W,
                                                    const float* __restrict__ b,
                                                    const float* __restrict__ g,
                                                    const float* __restrict__ be,
                                                    float* __restrict__ out) {
    __shared__ float Wl[DD * DD];   // 64 KB
    __shared__ float Al[32 * DD];   // 16 KB
    const int tid = threadIdx.x;
    for (int i = tid * 4; i < DD * DD; i += 1024)
        *(float4*)(Wl + i) = *(const float4*)(W + i);
    const int wave = tid >> 6, lane = tid & 63;
    const float2 bb = *(const float2*)(b + 2 * lane);
    const float2 gg = *(const float2*)(g + 2 * lane);
    const float2 bt = *(const float2*)(be + 2 * lane);
    for (int grp = blockIdx.x; grp < NN / 32; grp += gridDim.x) {
        const size_t base = (size_t)grp * 32;
        __syncthreads();   // W ready (first iter) / previous Al readers done
        for (int i = tid * 4; i < 32 * DD; i += 1024) {
            const ushort4 u = *(const ushort4*)(agg + base * DD + i);
            float4 v;
            v.x = __uint_as_float((unsigned)u.x << 16);
            v.y = __uint_as_float((unsigned)u.y << 16);
            v.z = __uint_as_float((unsigned)u.z << 16);
            v.w = __uint_as_float((unsigned)u.w << 16);
            *(float4*)(Al + i) = v;
        }
        __syncthreads();
        float ax[8], ay[8];
        #pragma unroll
        for (int r = 0; r < 8; ++r) { ax[r] = 0.f; ay[r] = 0.f; }
        const float* Arow = Al + wave * 8 * DD;
        for (int k = 0; k < DD; k += 4) {
            const float2 w0 = *(const float2*)(Wl + (k + 0) * DD + 2 * lane);
            const float2 w1 = *(const float2*)(Wl + (k + 1) * DD + 2 * lane);
            const float2 w2 = *(const float2*)(Wl + (k + 2) * DD + 2 * lane);
            const float2 w3 = *(const float2*)(Wl + (k + 3) * DD + 2 * lane);
            #pragma unroll
            for (int r = 0; r < 8; ++r) {
                const float4 xv = *(const float4*)(Arow + r * DD + k);
                ax[r] = fmaf(xv.x, w0.x, ax[r]); ay[r] = fmaf(xv.x, w0.y, ay[r]);
                ax[r] = fmaf(xv.y, w1.x, ax[r]); ay[r] = fmaf(xv.y, w1.y, ay[r]);
                ax[r] = fmaf(xv.z, w2.x, ax[r]); ay[r] = fmaf(xv.z, w2.y, ay[r]);
                ax[r] = fmaf(xv.w, w3.x, ax[r]); ay[r] = fmaf(xv.w, w3.y, ay[r]);
            }
        }
        #pragma unroll
        for (int r = 0; r < 8; ++r) {
            const size_t row = base + wave * 8 + r;
            const float2 xr = *(const float2*)(x + row * DD + 2 * lane);
            const float h0 = ax[r] + bb.x + xr.x;
            const float h1 = ay[r] + bb.y + xr.y;
            float sum = h0 + h1;
            #pragma unroll
            for (int off = 32; off; off >>= 1) sum += __shfl_xor(sum, off);
            const float mu = sum * (1.f / 128.f);
            const float e0 = h0 - mu, e1 = h1 - mu;
            float s2 = e0 * e0 + e1 * e1;
            #pragma unroll
            for (int off = 32; off; off >>= 1) s2 += __shfl_xor(s2, off);
            const float inv = rsqrtf(s2 * (1.f / 128.f) + EPSV);
            float2 o;
            o.x = fmaxf(0.f, e0 * inv * gg.x + bt.x);
            o.y = fmaxf(0.f, e1 * inv * gg.y + bt.y);
            *(float2*)(out + row * DD + 2 * lane) = o;
        }
    }
}

extern "C" void kernel_launch(void* const* d_in, const int* in_sizes, int n_in,
                              void* d_out, int out_size, void* d_ws, size_t ws_size,
                              hipStream_t stream) {
    const float* x  = (const float*)d_in[0];
    const int*   ei = (const int*)d_in[1];      // raw; width detected on device
    const float* W  = (const float*)d_in[2];
    const float* b  = (const float*)d_in[3];
    const float* g  = (const float*)d_in[4];
    const float* be = (const float*)d_in[5];
    float* out = (float*)d_out;

    char* ws = (char*)d_ws;
    size_t off = 0;
    unsigned short* xb  = (unsigned short*)(ws + off); off += (size_t)NN * DD * 2;  // 25.6 MB
    unsigned short* agg = (unsigned short*)(ws + off); off += (size_t)NN * DD * 2;  // 25.6 MB
    int*   e32   = (int*)(ws + off);   off += (size_t)2 * NE * 4;    // 12.8 MB
    int*   ssrc  = (int*)(ws + off);   off += (size_t)NE * 4;        // 6.4 MB
    int*   cnt   = (int*)(ws + off);   off += (size_t)NN * 4;
    int*   start = (int*)(ws + off);   off += (size_t)NN * 4;
    int*   fill  = (int*)(ws + off);   off += (size_t)NN * 4;
    float* dis   = (float*)(ws + off); off += (size_t)NN * 4;
    int*   flagc = (int*)(ws + off);   off += 256;                   // [flag, cursor]

    hipMemsetAsync(cnt, 0, (size_t)NN * 4, stream);
    hipMemsetAsync(flagc, 0, 256, stream);

    detect_kernel<<<16, 256, 0, stream>>>((const unsigned*)ei, flagc);
    convert_kernel<<<2048, 256, 0, stream>>>(ei, e32, flagc, x, xb);
    count_kernel<<<NPART * NCHUNK, 256, 0, stream>>>(e32, cnt);
    alloc_kernel<<<(NN + 255) / 256, 256, 0, stream>>>(cnt, start, fill, dis, flagc + 1);
    scatter_kernel<<<NPART * NCHUNK, 256, 0, stream>>>(e32, fill, ssrc);
    agg_kernel<<<NN / 4, 256, 0, stream>>>(xb, ssrc, start, cnt, dis, agg);
    gemm2_kernel<<<512, 256, 0, stream>>>(agg, x, W, b, g, be, out);
}

// Round 4
// 401.552 us; speedup vs baseline: 1.2975x; 1.1245x over previous
//
#include <hip/hip_runtime.h>
#include <cstdint>
#include <cstddef>

#define NN 100000
#define NE 1600000
#define DD 128
#define EPSV 1e-5f
#define NPART 8
#define PSIZE (NN / NPART)          // 12500 nodes per partition
#define NCHUNK 256
#define CSZ (NE / NCHUNK)           // 6250 edges per chunk

// RNE float->bf16 (no NaN handling; inputs are finite randn-scale values)
static __device__ inline unsigned short f2bf(float f) {
    unsigned u = __float_as_uint(f);
    unsigned r = (u + 0x7fffu + ((u >> 16) & 1u)) >> 16;
    return (unsigned short)r;
}

static __device__ inline float bflo(unsigned u) { return __uint_as_float(u << 16); }
static __device__ inline float bfhi(unsigned u) { return __uint_as_float(u & 0xffff0000u); }

// ---------------------------------------------------------------------------
// Edge dtype detection: reference says int64, but JAX default x64-off often
// yields int32. For int64 (little-endian, values < 2^31) every odd 32-bit
// word is 0. Sample 4096 odd words; any nonzero => int32 layout.
// ---------------------------------------------------------------------------
__global__ void detect_kernel(const unsigned* __restrict__ raw, int* __restrict__ flag) {
    int i = blockIdx.x * blockDim.x + threadIdx.x;
    if (i >= 4096) return;
    size_t idx = (size_t)i * 780 + 1;           // odd, max 3,194,101 < 2*NE
    if (raw[idx] != 0) atomicOr(flag, 1);
}

// Fused: edge normalization to int32 + in-degree count + x -> bf16 copy.
__global__ void convert_kernel(const int* __restrict__ raw, int* __restrict__ e32,
                               const int* __restrict__ flag,
                               const float* __restrict__ x, unsigned short* __restrict__ xb,
                               int* __restrict__ cnt) {
    const int is32 = *flag;
    const int stride = gridDim.x * blockDim.x;
    const int tid0 = blockIdx.x * blockDim.x + threadIdx.x;
    for (int i = tid0; i < 2 * NE; i += stride) {
        const int v = is32 ? raw[i] : raw[2 * (size_t)i];   // int64: take low word
        e32[i] = v;
        if (i >= NE) atomicAdd(&cnt[v], 1);                 // dst half -> degree
    }
    for (int i = tid0; i < NN * DD / 4; i += stride) {
        const float4 v = *(const float4*)(x + (size_t)i * 4);
        ushort4 o;
        o.x = f2bf(v.x); o.y = f2bf(v.y); o.z = f2bf(v.z); o.w = f2bf(v.w);
        *(ushort4*)(xb + (size_t)i * 4) = o;
    }
}

// bucket allocation: block-scan of counts + one atomic per block for base.
// Also writes fill cursors and dis = rsqrt(deg) with deg = cnt + 1 (self-loop).
__global__ void alloc_kernel(const int* __restrict__ cnt, int* __restrict__ start,
                             int* __restrict__ fill, float* __restrict__ dis,
                             int* __restrict__ cursor) {
    __shared__ int sdata[256];
    __shared__ int sbase;
    const int tid = threadIdx.x;
    const int v = blockIdx.x * 256 + tid;
    const int c = (v < NN) ? cnt[v] : 0;
    sdata[tid] = c;
    __syncthreads();
    #pragma unroll
    for (int off = 1; off < 256; off <<= 1) {
        int t = (tid >= off) ? sdata[tid - off] : 0;
        __syncthreads();
        sdata[tid] += t;
        __syncthreads();
    }
    const int excl = sdata[tid] - c;
    const int total = sdata[255];
    if (tid == 0) sbase = atomicAdd(cursor, total);
    __syncthreads();
    if (v < NN) {
        const int st = sbase + excl;
        start[v] = st;
        fill[v] = st;
        dis[v] = rsqrtf((float)(c + 1));
    }
}

// scatter edge sources into per-dst buckets, dst-partitioned so all writers
// of partition p sit on one XCD (b%8==p under round-robin dispatch) -> the
// ssrc region stays in that XCD's L2, no cross-XCD line ping-pong.
__global__ void scatter_kernel(const int* __restrict__ e32, int* __restrict__ fill,
                               int* __restrict__ ssrc) {
    const int part = blockIdx.x & (NPART - 1);
    const int chunk = blockIdx.x >> 3;
    const int lo = part * PSIZE, hi = lo + PSIZE;
    const int e0 = chunk * CSZ, e1 = e0 + CSZ;
    for (int e = e0 + threadIdx.x; e < e1; e += 256) {
        const int d = e32[NE + e];
        if (d >= lo && d < hi) {
            const int s = e32[e];
            const int p = atomicAdd(&fill[d], 1);
            ssrc[p] = s;
        }
    }
}

// One wave per node, 4-deep edge unroll for memory-level parallelism:
//   agg[n] = sum_e dis[s]*dis[n]*x[s] + dis[n]^2*x[n]   (bf16 in, f32 acc)
// Lane l owns cols (2l, 2l+1).
__global__ void agg_kernel(const unsigned short* __restrict__ xb,
                           const int* __restrict__ ssrc, const int* __restrict__ start,
                           const int* __restrict__ cnt, const float* __restrict__ dis,
                           unsigned short* __restrict__ agg) {
    const int wave = threadIdx.x >> 6, lane = threadIdx.x & 63;
    const int node = blockIdx.x * 4 + wave;
    if (node >= NN) return;
    const float dv = dis[node];
    const unsigned us = *(const unsigned*)(xb + (size_t)node * DD + 2 * lane);
    float accx = dv * dv * bflo(us);
    float accy = dv * dv * bfhi(us);
    const int s0 = start[node];
    const int c = cnt[node];
    for (int chunk = 0; chunk < c; chunk += 64) {
        const int rem0 = c - chunk;
        const int rem = rem0 < 64 ? rem0 : 64;
        int sj = 0; float dsj = 0.f;
        if (lane < rem) {
            sj = ssrc[s0 + chunk + lane];
            dsj = dis[sj];
        }
        int j = 0;
        for (; j + 4 <= rem; j += 4) {
            const int i0 = __builtin_amdgcn_readlane(sj, j);
            const int i1 = __builtin_amdgcn_readlane(sj, j + 1);
            const int i2 = __builtin_amdgcn_readlane(sj, j + 2);
            const int i3 = __builtin_amdgcn_readlane(sj, j + 3);
            const float w0 = __uint_as_float(__builtin_amdgcn_readlane(__float_as_uint(dsj), j)) * dv;
            const float w1 = __uint_as_float(__builtin_amdgcn_readlane(__float_as_uint(dsj), j + 1)) * dv;
            const float w2 = __uint_as_float(__builtin_amdgcn_readlane(__float_as_uint(dsj), j + 2)) * dv;
            const float w3 = __uint_as_float(__builtin_amdgcn_readlane(__float_as_uint(dsj), j + 3)) * dv;
            const unsigned v0 = *(const unsigned*)(xb + (size_t)i0 * DD + 2 * lane);
            const unsigned v1 = *(const unsigned*)(xb + (size_t)i1 * DD + 2 * lane);
            const unsigned v2 = *(const unsigned*)(xb + (size_t)i2 * DD + 2 * lane);
            const unsigned v3 = *(const unsigned*)(xb + (size_t)i3 * DD + 2 * lane);
            accx = fmaf(w0, bflo(v0), accx); accy = fmaf(w0, bfhi(v0), accy);
            accx = fmaf(w1, bflo(v1), accx); accy = fmaf(w1, bfhi(v1), accy);
            accx = fmaf(w2, bflo(v2), accx); accy = fmaf(w2, bfhi(v2), accy);
            accx = fmaf(w3, bflo(v3), accx); accy = fmaf(w3, bfhi(v3), accy);
        }
        for (; j < rem; ++j) {
            const int s = __builtin_amdgcn_readlane(sj, j);
            const float w = __uint_as_float(__builtin_amdgcn_readlane(__float_as_uint(dsj), j)) * dv;
            const unsigned uv = *(const unsigned*)(xb + (size_t)s * DD + 2 * lane);
            accx = fmaf(w, bflo(uv), accx);
            accy = fmaf(w, bfhi(uv), accy);
        }
    }
    ushort2 st; st.x = f2bf(accx); st.y = f2bf(accy);
    *(ushort2*)(agg + (size_t)node * DD + 2 * lane) = st;
}

// h = agg @ W + b + x; LayerNorm; ReLU. W (64KB f32) + 32 agg rows
// (expanded to f32, 16KB) in LDS. Each wave computes 8 rows; lane l holds
// output cols (2l, 2l+1). 512 blocks -> 2 blocks/CU (LDS-limited).
__global__ __launch_bounds__(256) void gemm2_kernel(const unsigned short* __restrict__ agg,
                                                    const float* __restrict__ x,
                                                    const float* __restrict__ W,
                                                    const float* __restrict__ b,
                                                    const float* __restrict__ g,
                                                    const float* __restrict__ be,
                                                    float* __restrict__ out) {
    __shared__ float Wl[DD * DD];   // 64 KB
    __shared__ float Al[32 * DD];   // 16 KB
    const int tid = threadIdx.x;
    for (int i = tid * 4; i < DD * DD; i += 1024)
        *(float4*)(Wl + i) = *(const float4*)(W + i);
    const int wave = tid >> 6, lane = tid & 63;
    const float2 bb = *(const float2*)(b + 2 * lane);
    const float2 gg = *(const float2*)(g + 2 * lane);
    const float2 bt = *(const float2*)(be + 2 * lane);
    for (int grp = blockIdx.x; grp < NN / 32; grp += gridDim.x) {
        const size_t base = (size_t)grp * 32;
        __syncthreads();   // W ready (first iter) / previous Al readers done
        for (int i = tid * 4; i < 32 * DD; i += 1024) {
            const ushort4 u = *(const ushort4*)(agg + base * DD + i);
            float4 v;
            v.x = __uint_as_float((unsigned)u.x << 16);
            v.y = __uint_as_float((unsigned)u.y << 16);
            v.z = __uint_as_float((unsigned)u.z << 16);
            v.w = __uint_as_float((unsigned)u.w << 16);
            *(float4*)(Al + i) = v;
        }
        __syncthreads();
        float ax[8], ay[8];
        #pragma unroll
        for (int r = 0; r < 8; ++r) { ax[r] = 0.f; ay[r] = 0.f; }
        const float* Arow = Al + wave * 8 * DD;
        for (int k = 0; k < DD; k += 4) {
            const float2 w0 = *(const float2*)(Wl + (k + 0) * DD + 2 * lane);
            const float2 w1 = *(const float2*)(Wl + (k + 1) * DD + 2 * lane);
            const float2 w2 = *(const float2*)(Wl + (k + 2) * DD + 2 * lane);
            const float2 w3 = *(const float2*)(Wl + (k + 3) * DD + 2 * lane);
            #pragma unroll
            for (int r = 0; r < 8; ++r) {
                const float4 xv = *(const float4*)(Arow + r * DD + k);
                ax[r] = fmaf(xv.x, w0.x, ax[r]); ay[r] = fmaf(xv.x, w0.y, ay[r]);
                ax[r] = fmaf(xv.y, w1.x, ax[r]); ay[r] = fmaf(xv.y, w1.y, ay[r]);
                ax[r] = fmaf(xv.z, w2.x, ax[r]); ay[r] = fmaf(xv.z, w2.y, ay[r]);
                ax[r] = fmaf(xv.w, w3.x, ax[r]); ay[r] = fmaf(xv.w, w3.y, ay[r]);
            }
        }
        #pragma unroll
        for (int r = 0; r < 8; ++r) {
            const size_t row = base + wave * 8 + r;
            const float2 xr = *(const float2*)(x + row * DD + 2 * lane);
            const float h0 = ax[r] + bb.x + xr.x;
            const float h1 = ay[r] + bb.y + xr.y;
            float sum = h0 + h1;
            #pragma unroll
            for (int off = 32; off; off >>= 1) sum += __shfl_xor(sum, off);
            const float mu = sum * (1.f / 128.f);
            const float e0 = h0 - mu, e1 = h1 - mu;
            float s2 = e0 * e0 + e1 * e1;
            #pragma unroll
            for (int off = 32; off; off >>= 1) s2 += __shfl_xor(s2, off);
            const float inv = rsqrtf(s2 * (1.f / 128.f) + EPSV);
            float2 o;
            o.x = fmaxf(0.f, e0 * inv * gg.x + bt.x);
            o.y = fmaxf(0.f, e1 * inv * gg.y + bt.y);
            *(float2*)(out + row * DD + 2 * lane) = o;
        }
    }
}

extern "C" void kernel_launch(void* const* d_in, const int* in_sizes, int n_in,
                              void* d_out, int out_size, void* d_ws, size_t ws_size,
                              hipStream_t stream) {
    const float* x  = (const float*)d_in[0];
    const int*   ei = (const int*)d_in[1];      // raw; width detected on device
    const float* W  = (const float*)d_in[2];
    const float* b  = (const float*)d_in[3];
    const float* g  = (const float*)d_in[4];
    const float* be = (const float*)d_in[5];
    float* out = (float*)d_out;

    char* ws = (char*)d_ws;
    size_t off = 0;
    unsigned short* xb  = (unsigned short*)(ws + off); off += (size_t)NN * DD * 2;  // 25.6 MB
    unsigned short* agg = (unsigned short*)(ws + off); off += (size_t)NN * DD * 2;  // 25.6 MB
    int*   e32   = (int*)(ws + off);   off += (size_t)2 * NE * 4;    // 12.8 MB
    int*   ssrc  = (int*)(ws + off);   off += (size_t)NE * 4;        // 6.4 MB
    int*   cnt   = (int*)(ws + off);   off += (size_t)NN * 4;
    int*   start = (int*)(ws + off);   off += (size_t)NN * 4;
    int*   fill  = (int*)(ws + off);   off += (size_t)NN * 4;
    float* dis   = (float*)(ws + off); off += (size_t)NN * 4;
    int*   flagc = (int*)(ws + off);   off += 256;                   // [flag, cursor]

    hipMemsetAsync(cnt, 0, (size_t)NN * 4, stream);
    hipMemsetAsync(flagc, 0, 256, stream);

    detect_kernel<<<16, 256, 0, stream>>>((const unsigned*)ei, flagc);
    convert_kernel<<<2048, 256, 0, stream>>>(ei, e32, flagc, x, xb, cnt);
    alloc_kernel<<<(NN + 255) / 256, 256, 0, stream>>>(cnt, start, fill, dis, flagc + 1);
    scatter_kernel<<<NPART * NCHUNK, 256, 0, stream>>>(e32, fill, ssrc);
    agg_kernel<<<NN / 4, 256, 0, stream>>>(xb, ssrc, start, cnt, dis, agg);
    gemm2_kernel<<<512, 256, 0, stream>>>(agg, x, W, b, g, be, out);
}

// Round 5
// 347.122 us; speedup vs baseline: 1.5010x; 1.1568x over previous
//
#include <hip/hip_runtime.h>
#include <cstdint>
#include <cstddef>

#define NN 100000
#define NE 1600000
#define DD 128
#define EPSV 1e-5f
#define NPART 8
#define PSIZE (NN / NPART)          // 12500 nodes per partition
#define NCHUNK 256
#define CSZ (NE / NCHUNK)           // 6250 edges per chunk

typedef __attribute__((ext_vector_type(8))) short bf16x8;
typedef __attribute__((ext_vector_type(4))) float f32x4;

// RNE float->bf16 (no NaN handling; inputs are finite randn-scale values)
static __device__ inline unsigned short f2bf(float f) {
    unsigned u = __float_as_uint(f);
    unsigned r = (u + 0x7fffu + ((u >> 16) & 1u)) >> 16;
    return (unsigned short)r;
}

static __device__ inline float bflo(unsigned u) { return __uint_as_float(u << 16); }
static __device__ inline float bfhi(unsigned u) { return __uint_as_float(u & 0xffff0000u); }

// ---------------------------------------------------------------------------
// Edge dtype detection: reference says int64, but JAX default x64-off often
// yields int32. For int64 (little-endian, values < 2^31) every odd 32-bit
// word is 0. Sample 4096 odd words; any nonzero => int32 layout.
// ---------------------------------------------------------------------------
__global__ void detect_kernel(const unsigned* __restrict__ raw, int* __restrict__ flag) {
    int i = blockIdx.x * blockDim.x + threadIdx.x;
    if (i >= 4096) return;
    size_t idx = (size_t)i * 780 + 1;           // odd, max 3,194,101 < 2*NE
    if (raw[idx] != 0) atomicOr(flag, 1);
}

// Fused: edge normalization to int32 + in-degree count + x,W -> bf16 copies.
__global__ void convert_kernel(const int* __restrict__ raw, int* __restrict__ e32,
                               const int* __restrict__ flag,
                               const float* __restrict__ x, unsigned short* __restrict__ xb,
                               const float* __restrict__ W, unsigned short* __restrict__ wb,
                               int* __restrict__ cnt) {
    const int is32 = *flag;
    const int stride = gridDim.x * blockDim.x;
    const int tid0 = blockIdx.x * blockDim.x + threadIdx.x;
    for (int i = tid0; i < 2 * NE; i += stride) {
        const int v = is32 ? raw[i] : raw[2 * (size_t)i];   // int64: take low word
        e32[i] = v;
        if (i >= NE) atomicAdd(&cnt[v], 1);                 // dst half -> degree
    }
    for (int i = tid0; i < NN * DD / 4; i += stride) {
        const float4 v = *(const float4*)(x + (size_t)i * 4);
        ushort4 o;
        o.x = f2bf(v.x); o.y = f2bf(v.y); o.z = f2bf(v.z); o.w = f2bf(v.w);
        *(ushort4*)(xb + (size_t)i * 4) = o;
    }
    for (int i = tid0; i < DD * DD / 4; i += stride) {
        const float4 v = *(const float4*)(W + (size_t)i * 4);
        ushort4 o;
        o.x = f2bf(v.x); o.y = f2bf(v.y); o.z = f2bf(v.z); o.w = f2bf(v.w);
        *(ushort4*)(wb + (size_t)i * 4) = o;
    }
}

// bucket allocation: block-scan of counts + one atomic per block for base.
// Also writes fill cursors and dis = rsqrt(deg) with deg = cnt + 1 (self-loop).
__global__ void alloc_kernel(const int* __restrict__ cnt, int* __restrict__ start,
                             int* __restrict__ fill, float* __restrict__ dis,
                             int* __restrict__ cursor) {
    __shared__ int sdata[256];
    __shared__ int sbase;
    const int tid = threadIdx.x;
    const int v = blockIdx.x * 256 + tid;
    const int c = (v < NN) ? cnt[v] : 0;
    sdata[tid] = c;
    __syncthreads();
    #pragma unroll
    for (int off = 1; off < 256; off <<= 1) {
        int t = (tid >= off) ? sdata[tid - off] : 0;
        __syncthreads();
        sdata[tid] += t;
        __syncthreads();
    }
    const int excl = sdata[tid] - c;
    const int total = sdata[255];
    if (tid == 0) sbase = atomicAdd(cursor, total);
    __syncthreads();
    if (v < NN) {
        const int st = sbase + excl;
        start[v] = st;
        fill[v] = st;
        dis[v] = rsqrtf((float)(c + 1));
    }
}

// scatter edge sources into per-dst buckets, dst-partitioned so all writers
// of partition p sit on one XCD (b%8==p under round-robin dispatch) -> the
// ssrc region stays in that XCD's L2, no cross-XCD line ping-pong.
__global__ void scatter_kernel(const int* __restrict__ e32, int* __restrict__ fill,
                               int* __restrict__ ssrc) {
    const int part = blockIdx.x & (NPART - 1);
    const int chunk = blockIdx.x >> 3;
    const int lo = part * PSIZE, hi = lo + PSIZE;
    const int e0 = chunk * CSZ, e1 = e0 + CSZ;
    for (int e = e0 + threadIdx.x; e < e1; e += 256) {
        const int d = e32[NE + e];
        if (d >= lo && d < hi) {
            const int s = e32[e];
            const int p = atomicAdd(&fill[d], 1);
            ssrc[p] = s;
        }
    }
}

// One wave per node, 4-deep edge unroll for memory-level parallelism:
//   agg[n] = sum_e dis[s]*dis[n]*x[s] + dis[n]^2*x[n]   (bf16 in, f32 acc)
// Lane l owns cols (2l, 2l+1).
__global__ void agg_kernel(const unsigned short* __restrict__ xb,
                           const int* __restrict__ ssrc, const int* __restrict__ start,
                           const int* __restrict__ cnt, const float* __restrict__ dis,
                           unsigned short* __restrict__ agg) {
    const int wave = threadIdx.x >> 6, lane = threadIdx.x & 63;
    const int node = blockIdx.x * 4 + wave;
    if (node >= NN) return;
    const float dv = dis[node];
    const unsigned us = *(const unsigned*)(xb + (size_t)node * DD + 2 * lane);
    float accx = dv * dv * bflo(us);
    float accy = dv * dv * bfhi(us);
    const int s0 = start[node];
    const int c = cnt[node];
    for (int chunk = 0; chunk < c; chunk += 64) {
        const int rem0 = c - chunk;
        const int rem = rem0 < 64 ? rem0 : 64;
        int sj = 0; float dsj = 0.f;
        if (lane < rem) {
            sj = ssrc[s0 + chunk + lane];
            dsj = dis[sj];
        }
        int j = 0;
        for (; j + 4 <= rem; j += 4) {
            const int i0 = __builtin_amdgcn_readlane(sj, j);
            const int i1 = __builtin_amdgcn_readlane(sj, j + 1);
            const int i2 = __builtin_amdgcn_readlane(sj, j + 2);
            const int i3 = __builtin_amdgcn_readlane(sj, j + 3);
            const float w0 = __uint_as_float(__builtin_amdgcn_readlane(__float_as_uint(dsj), j)) * dv;
            const float w1 = __uint_as_float(__builtin_amdgcn_readlane(__float_as_uint(dsj), j + 1)) * dv;
            const float w2 = __uint_as_float(__builtin_amdgcn_readlane(__float_as_uint(dsj), j + 2)) * dv;
            const float w3 = __uint_as_float(__builtin_amdgcn_readlane(__float_as_uint(dsj), j + 3)) * dv;
            const unsigned v0 = *(const unsigned*)(xb + (size_t)i0 * DD + 2 * lane);
            const unsigned v1 = *(const unsigned*)(xb + (size_t)i1 * DD + 2 * lane);
            const unsigned v2 = *(const unsigned*)(xb + (size_t)i2 * DD + 2 * lane);
            const unsigned v3 = *(const unsigned*)(xb + (size_t)i3 * DD + 2 * lane);
            accx = fmaf(w0, bflo(v0), accx); accy = fmaf(w0, bfhi(v0), accy);
            accx = fmaf(w1, bflo(v1), accx); accy = fmaf(w1, bfhi(v1), accy);
            accx = fmaf(w2, bflo(v2), accx); accy = fmaf(w2, bfhi(v2), accy);
            accx = fmaf(w3, bflo(v3), accx); accy = fmaf(w3, bfhi(v3), accy);
        }
        for (; j < rem; ++j) {
            const int s = __builtin_amdgcn_readlane(sj, j);
            const float w = __uint_as_float(__builtin_amdgcn_readlane(__float_as_uint(dsj), j)) * dv;
            const unsigned uv = *(const unsigned*)(xb + (size_t)s * DD + 2 * lane);
            accx = fmaf(w, bflo(uv), accx);
            accy = fmaf(w, bfhi(uv), accy);
        }
    }
    ushort2 st; st.x = f2bf(accx); st.y = f2bf(accy);
    *(ushort2*)(agg + (size_t)node * DD + 2 * lane) = st;
}

// MFMA GEMM + fused epilogue: h = agg @ W + b + x; LayerNorm; ReLU.
// One wave per 16-node row-block; W held entirely in registers as 32 B-frags
// (reused across grid-stride loop); no LDS, no barriers.
// mfma_f32_16x16x32_bf16 layouts (m89-verified C/D):
//   A: lane l -> A[l&15][ (l>>4)*8 + j ]   (8 consecutive bf16 = 16B load)
//   B: lane l -> B[ (l>>4)*8 + j ][ l&15 ]
//   D: lane l, reg r -> D[ (l>>4)*4 + r ][ l&15 ]
__global__ __launch_bounds__(256) void gemm2_kernel(const unsigned short* __restrict__ agg,
                                                    const unsigned short* __restrict__ xb,
                                                    const unsigned short* __restrict__ wb,
                                                    const float* __restrict__ b,
                                                    const float* __restrict__ g,
                                                    const float* __restrict__ be,
                                                    float* __restrict__ out) {
    const int wave = threadIdx.x >> 6, lane = threadIdx.x & 63;
    const int grp = lane >> 4;       // 0..3
    const int lc  = lane & 15;
    // Preload all B fragments: bfr[kblk][ctile]
    bf16x8 bfr[4][8];
    #pragma unroll
    for (int kb = 0; kb < 4; ++kb) {
        #pragma unroll
        for (int t = 0; t < 8; ++t) {
            bf16x8 v;
            #pragma unroll
            for (int j = 0; j < 8; ++j)
                v[j] = (short)wb[(size_t)(kb * 32 + grp * 8 + j) * DD + t * 16 + lc];
            bfr[kb][t] = v;
        }
    }
    float bbv[8], ggv[8], btv[8];
    #pragma unroll
    for (int t = 0; t < 8; ++t) {
        bbv[t] = b[t * 16 + lc];
        ggv[t] = g[t * 16 + lc];
        btv[t] = be[t * 16 + lc];
    }
    const int nrb = NN / 16;   // 6250
    const int nw = gridDim.x * 4;
    for (int rb = blockIdx.x * 4 + wave; rb < nrb; rb += nw) {
        const unsigned short* ap = agg + (size_t)(rb * 16 + lc) * DD + grp * 8;
        f32x4 acc[8];
        #pragma unroll
        for (int t = 0; t < 8; ++t) acc[t] = (f32x4){0.f, 0.f, 0.f, 0.f};
        #pragma unroll
        for (int kb = 0; kb < 4; ++kb) {
            const bf16x8 a = *(const bf16x8*)(ap + kb * 32);
            #pragma unroll
            for (int t = 0; t < 8; ++t)
                acc[t] = __builtin_amdgcn_mfma_f32_16x16x32_bf16(a, bfr[kb][t], acc[t], 0, 0, 0);
        }
        // epilogue: rows r0+reg (reg=0..3) live in this 16-lane group
        const int r0 = rb * 16 + grp * 4;
        float h[8][4];
        float rs[4] = {0.f, 0.f, 0.f, 0.f};
        #pragma unroll
        for (int reg = 0; reg < 4; ++reg) {
            #pragma unroll
            for (int t = 0; t < 8; ++t) {
                const unsigned xr = xb[(size_t)(r0 + reg) * DD + t * 16 + lc];
                const float hv = acc[t][reg] + bbv[t] + bflo(xr);
                h[t][reg] = hv;
                rs[reg] += hv;
            }
        }
        #pragma unroll
        for (int reg = 0; reg < 4; ++reg) {
            #pragma unroll
            for (int off = 8; off; off >>= 1) rs[reg] += __shfl_xor(rs[reg], off);
        }
        float mu[4], s2[4] = {0.f, 0.f, 0.f, 0.f};
        #pragma unroll
        for (int reg = 0; reg < 4; ++reg) {
            mu[reg] = rs[reg] * (1.f / 128.f);
            #pragma unroll
            for (int t = 0; t < 8; ++t) {
                const float e = h[t][reg] - mu[reg];
                s2[reg] += e * e;
            }
            #pragma unroll
            for (int off = 8; off; off >>= 1) s2[reg] += __shfl_xor(s2[reg], off);
        }
        #pragma unroll
        for (int reg = 0; reg < 4; ++reg) {
            const float inv = rsqrtf(s2[reg] * (1.f / 128.f) + EPSV);
            #pragma unroll
            for (int t = 0; t < 8; ++t) {
                const float o = fmaxf(0.f, (h[t][reg] - mu[reg]) * inv * ggv[t] + btv[t]);
                out[(size_t)(r0 + reg) * DD + t * 16 + lc] = o;
            }
        }
    }
}

extern "C" void kernel_launch(void* const* d_in, const int* in_sizes, int n_in,
                              void* d_out, int out_size, void* d_ws, size_t ws_size,
                              hipStream_t stream) {
    const float* x  = (const float*)d_in[0];
    const int*   ei = (const int*)d_in[1];      // raw; width detected on device
    const float* W  = (const float*)d_in[2];
    const float* b  = (const float*)d_in[3];
    const float* g  = (const float*)d_in[4];
    const float* be = (const float*)d_in[5];
    float* out = (float*)d_out;

    char* ws = (char*)d_ws;
    size_t off = 0;
    unsigned short* xb  = (unsigned short*)(ws + off); off += (size_t)NN * DD * 2;  // 25.6 MB
    unsigned short* agg = (unsigned short*)(ws + off); off += (size_t)NN * DD * 2;  // 25.6 MB
    int*   e32   = (int*)(ws + off);   off += (size_t)2 * NE * 4;    // 12.8 MB
    int*   ssrc  = (int*)(ws + off);   off += (size_t)NE * 4;        // 6.4 MB
    unsigned short* wb = (unsigned short*)(ws + off); off += (size_t)DD * DD * 2;   // 32 KB
    int*   cnt   = (int*)(ws + off);   off += (size_t)NN * 4;
    int*   start = (int*)(ws + off);   off += (size_t)NN * 4;
    int*   fill  = (int*)(ws + off);   off += (size_t)NN * 4;
    float* dis   = (float*)(ws + off); off += (size_t)NN * 4;
    int*   flagc = (int*)(ws + off);   off += 256;                   // [flag, cursor]

    hipMemsetAsync(cnt, 0, (size_t)NN * 4, stream);
    hipMemsetAsync(flagc, 0, 256, stream);

    detect_kernel<<<16, 256, 0, stream>>>((const unsigned*)ei, flagc);
    convert_kernel<<<2048, 256, 0, stream>>>(ei, e32, flagc, x, xb, W, wb, cnt);
    alloc_kernel<<<(NN + 255) / 256, 256, 0, stream>>>(cnt, start, fill, dis, flagc + 1);
    scatter_kernel<<<NPART * NCHUNK, 256, 0, stream>>>(e32, fill, ssrc);
    agg_kernel<<<NN / 4, 256, 0, stream>>>(xb, ssrc, start, cnt, dis, agg);
    gemm2_kernel<<<512, 256, 0, stream>>>(agg, xb, wb, b, g, be, out);
}